// Round 4
// baseline (6703.815 us; speedup 1.0000x reference)
//
#include <hip/hip_runtime.h>
#include <hip/hip_bf16.h>

// Problem constants
#define B_   32
#define S_   512
#define E_   512
#define H_   1024          // U_DIM
#define G4_  4096          // 4*U_DIM

typedef __attribute__((ext_vector_type(8))) short short8;
typedef __attribute__((ext_vector_type(4))) float f32x4;
typedef unsigned long long u64;

__device__ __forceinline__ float bf2f(ushort u) {
    union { unsigned u32; float f; } cv; cv.u32 = ((unsigned)u) << 16; return cv.f;
}
__device__ __forceinline__ ushort f2bf(float f) {
    union { float f; unsigned u; } cv; cv.f = f;
    unsigned u = cv.u;
    u += 0x7FFFu + ((u >> 16) & 1u);   // RNE
    return (ushort)(u >> 16);
}
__device__ __forceinline__ float tanh_fast(float x) {
    float e = __builtin_amdgcn_exp2f(x * 2.885390081777927f);
    return 1.0f - 2.0f * __builtin_amdgcn_rcpf(e + 1.0f);
}
__device__ __forceinline__ float sel4(int s, float a0, float a1, float a2, float a3) {
    return (s & 2) ? ((s & 1) ? a3 : a2) : ((s & 1) ? a1 : a0);
}

// ---------------- init: zero h0 (fp8) and wave-flags ----------------
__global__ void init_kernel(u64* hA, unsigned* flags) {
    int i = blockIdx.x * 256 + threadIdx.x;
    if (i < 4096) hA[i] = 0ull;       // 32 KB fp8 h state
    if (i < 512)  flags[i] = 0u;
}

// ---------------- W transpose: fp32 [E][G4] -> bf16 WT[n][k] ----------------
__global__ void transpose_w_kernel(const float* __restrict__ src, ushort* __restrict__ dst) {
    __shared__ float tile[32][33];
    int kx = blockIdx.y * 32;
    int nx = blockIdx.x * 32;
    int c  = threadIdx.x & 31;
    int r0 = threadIdx.x >> 5;
    for (int rr = r0; rr < 32; rr += 8)
        tile[rr][c] = src[(size_t)(kx + rr) * G4_ + nx + c];
    __syncthreads();
    for (int rr = r0; rr < 32; rr += 8)
        dst[(size_t)(nx + rr) * E_ + kx + c] = f2bf(tile[c][rr]);
}

// ---------------- U transpose: fp32 [H][G4] -> fp8(e4m3, x64) UT[n'][k], n'=j*4+g ----------------
__global__ void transpose_u_kernel(const float* __restrict__ src, unsigned* __restrict__ dst) {
    __shared__ float tile[32][33];
    int kx = blockIdx.y * 32;
    int nx = blockIdx.x * 32;
    int c  = threadIdx.x & 31;
    int r0 = threadIdx.x >> 5;
    for (int rr = r0; rr < 32; rr += 8)
        tile[rr][c] = src[(size_t)(kx + rr) * G4_ + nx + c];
    __syncthreads();
    int r  = threadIdx.x >> 3;    // n-index in tile 0..31
    int c3 = threadIdx.x & 7;     // k-quad
    int n  = nx + r;
    int np = (n & 1023) * 4 + (n >> 10);
    float v0 = tile[c3 * 4 + 0][r] * 64.0f;
    float v1 = tile[c3 * 4 + 1][r] * 64.0f;
    float v2 = tile[c3 * 4 + 2][r] * 64.0f;
    float v3 = tile[c3 * 4 + 3][r] * 64.0f;
    int pk = __builtin_amdgcn_cvt_pk_fp8_f32(v0, v1, 0, false);
    pk     = __builtin_amdgcn_cvt_pk_fp8_f32(v2, v3, pk, true);
    dst[((size_t)np * H_ + kx + c3 * 4) >> 2] = (unsigned)pk;
}

// ---------------- xW GEMM: emb[tok] @ W + b  -> xWT[t][n'][b] bf16 (coalesced via LDS) ----------------
__global__ __launch_bounds__(256, 1) void gemm_xw_kernel(
    const int* __restrict__ tokens, const float* __restrict__ emb,
    const ushort* __restrict__ WT,  const float* __restrict__ bias,
    ushort* __restrict__ xWT) {
    __shared__ u64 Cs[1024];          // [t'2][npl 64][b 32] ushorts = 1024 u64
    const int tid  = threadIdx.x;
    const int lane = tid & 63;
    const int w    = tid >> 6;
    const int jb   = blockIdx.x;      // 0..63  (j-block of 16)
    const int mb   = blockIdx.y;      // 0..255 (t-pair)
    const int lr = lane & 15, lq = lane >> 4;

    const int t    = mb * 2 + (w >> 1);
    const int brow = (w & 1) * 16 + lr;
    const int tok  = tokens[brow * S_ + t];
    const float* arow = emb + (size_t)tok * E_;

    f32x4 acc[4] = {{0,0,0,0},{0,0,0,0},{0,0,0,0},{0,0,0,0}};
    #pragma unroll 4
    for (int ks = 0; ks < E_ / 32; ++ks) {
        const float* ap = arow + ks * 32 + lq * 8;
        float4 a0 = *reinterpret_cast<const float4*>(ap);
        float4 a1 = *reinterpret_cast<const float4*>(ap + 4);
        short8 af;
        af[0] = (short)f2bf(a0.x); af[1] = (short)f2bf(a0.y);
        af[2] = (short)f2bf(a0.z); af[3] = (short)f2bf(a0.w);
        af[4] = (short)f2bf(a1.x); af[5] = (short)f2bf(a1.y);
        af[6] = (short)f2bf(a1.z); af[7] = (short)f2bf(a1.w);
        #pragma unroll
        for (int s = 0; s < 4; ++s) {
            const ushort* brow_p = WT + (size_t)(s * 1024 + jb * 16 + lr) * E_;
            short8 bf = *reinterpret_cast<const short8*>(brow_p + ks * 32 + lq * 8);
            acc[s] = __builtin_amdgcn_mfma_f32_16x16x32_bf16(af, bf, acc[s], 0, 0, 0);
        }
    }
    #pragma unroll
    for (int s = 0; s < 4; ++s) {
        float bv = bias[s * 1024 + jb * 16 + lr];
        u64 pk = 0;
        #pragma unroll
        for (int r = 0; r < 4; ++r)
            pk |= (u64)f2bf(acc[s][r] + bv) << (16 * r);   // 4 consecutive b
        int npl = lr * 4 + s;
        int b4  = (w & 1) * 4 + lq;
        Cs[((w >> 1) * 64 + npl) * 8 + b4] = pk;
    }
    __syncthreads();
    #pragma unroll
    for (int i = 0; i < 4; ++i) {
        int e   = tid + i * 256;          // u64 index 0..1023
        int tp  = e >> 9;
        int rem = e & 511;
        size_t base = ((size_t)(mb * 2 + tp) * G4_ + jb * 64) * B_;  // shorts
        *reinterpret_cast<u64*>(xWT + base + rem * 4) = Cs[e];
    }
}

// ---------------- persistent LSTM scan: wave-autonomous, zero LDS ----------------
// 256 blocks x 128 thr = 512 waves. Wave = 16 rows x 16 n'-cols, K=1024 fp8 MFMA.
// U fragments preloaded to VGPRs (step-invariant). h (fp8) exchanged via LLC
// (agent-scope relaxed = sc0+sc1). Per-wave flags, fully distributed polling.
__global__ __launch_bounds__(128, 1) void scan_kernel(
    const unsigned char* __restrict__ UT,  // fp8 [4096][1024]
    const ushort* __restrict__ xWT,        // bf16 [512][4096][32]
    const int* __restrict__ tokens,        // [32][512]
    u64* hA, u64* hB,                      // fp8 h [32][1024] ping-pong
    unsigned* flags,                       // [512] per-wave step counters
    float* __restrict__ out) {             // [3][32][1024] fp32
    const int lane = threadIdx.x & 63;
    const int w    = threadIdx.x >> 6;     // 0..1
    const int tile = blockIdx.x * 2 + w;   // 0..511
    const int lr = lane & 15, lq = lane >> 4;
    const int m0 = (tile & 1) * 16;        // row group
    const int cg = tile >> 1;              // col group 0..255
    const int ng = cg * 16 + lr;           // global n'
    const int g  = lr & 3;                 // gate id
    const int jg = ng >> 2;                // global j for this lane

    // step-invariant B fragments (U slice) -> 64 VGPRs
    long ub[32];
    #pragma unroll
    for (int ks = 0; ks < 32; ++ks)
        ub[ks] = *reinterpret_cast<const long*>(UT + (size_t)ng * H_ + ks * 32 + lq * 8);

    float creg[4] = {0, 0, 0, 0};
    float hreg[4] = {0, 0, 0, 0};
    const u64* hcur = hA;
    u64*       hnxt = hB;

    // prefetch t=0 inputs
    u64 xwv = *reinterpret_cast<const u64*>(xWT + ((size_t)0 * G4_ + ng) * B_ + m0 + lq * 4);
    int tok[4];
    #pragma unroll
    for (int r = 0; r < 4; ++r) tok[r] = tokens[(m0 + lq * 4 + r) * S_ + 0];

    for (int t = 0; t < S_; ++t) {
        if (t > 0) {
            // distributed poll: all 512 wave-flags >= t
            for (;;) {
                bool ok = true;
                #pragma unroll
                for (int i = 0; i < 8; ++i) {
                    unsigned f = __hip_atomic_load(&flags[lane + i * 64],
                                                   __ATOMIC_RELAXED, __HIP_MEMORY_SCOPE_AGENT);
                    ok = ok && (f >= (unsigned)t);
                }
                if (__all(ok)) break;
                __builtin_amdgcn_s_sleep(1);
            }
        }
        // A fragments straight from LLC (32 independent 8-B loads -> vmcnt pipeline)
        long ar[32];
        #pragma unroll
        for (int ks = 0; ks < 32; ++ks)
            ar[ks] = (long)__hip_atomic_load(hcur + (m0 + lr) * 128 + ks * 4 + lq,
                                             __ATOMIC_RELAXED, __HIP_MEMORY_SCOPE_AGENT);

        f32x4 acc0 = {0, 0, 0, 0}, acc1 = {0, 0, 0, 0};
        #pragma unroll
        for (int ks = 0; ks < 32; ks += 2) {
            acc0 = __builtin_amdgcn_mfma_f32_16x16x32_fp8_fp8(ar[ks],     ub[ks],     acc0, 0, 0, 0);
            acc1 = __builtin_amdgcn_mfma_f32_16x16x32_fp8_fp8(ar[ks + 1], ub[ks + 1], acc1, 0, 0, 0);
        }

        #pragma unroll
        for (int r = 0; r < 4; ++r) {
            float z  = (acc0[r] + acc1[r]) * (1.0f / 16384.0f) + bf2f((ushort)(xwv >> (16 * r)));
            float tg = tanh_fast(z);
            float x1 = __shfl_xor(tg, 1, 64);
            float x2 = __shfl_xor(tg, 2, 64);
            float x3 = __shfl_xor(tg, 3, 64);
            float tI = sel4(g,     tg, x1, x2, x3);
            float tF = sel4(g ^ 1, tg, x1, x2, x3);
            float tG = sel4(g ^ 2, tg, x1, x2, x3);
            float tO = sel4(g ^ 3, tg, x1, x2, x3);
            float cn = tF * creg[r] + tI * tG;
            float hn = tO * tanh_fast(cn);
            if (tok[r] != 0) { creg[r] = cn; hreg[r] = hn; }
        }

        if (t < S_ - 1) {
            // pack 4 j-values per row into u32 fp8 (x256 scale) on lanes lr==0
            #pragma unroll
            for (int r = 0; r < 4; ++r) {
                float h0 = hreg[r] * 256.0f;
                float h1 = __shfl_xor(h0, 4, 64);
                float h2 = __shfl_xor(h0, 8, 64);
                float h3 = __shfl_xor(h0, 12, 64);
                int pk = __builtin_amdgcn_cvt_pk_fp8_f32(h0, h1, 0, false);
                pk     = __builtin_amdgcn_cvt_pk_fp8_f32(h2, h3, pk, true);
                if (lr == 0) {
                    int row = m0 + lq * 4 + r;
                    __hip_atomic_store((unsigned*)hnxt + row * 256 + cg, (unsigned)pk,
                                       __ATOMIC_RELAXED, __HIP_MEMORY_SCOPE_AGENT);
                }
            }
            // release flag: orders wave's h stores (vmcnt drain) before visibility
            if (lane == 0)
                __hip_atomic_store(&flags[tile], (unsigned)(t + 1),
                                   __ATOMIC_RELEASE, __HIP_MEMORY_SCOPE_AGENT);
            // prefetch next step's xw/tok AFTER flag (keeps them off the release drain)
            xwv = *reinterpret_cast<const u64*>(xWT + ((size_t)(t + 1) * G4_ + ng) * B_ + m0 + lq * 4);
            #pragma unroll
            for (int r = 0; r < 4; ++r) tok[r] = tokens[(m0 + lq * 4 + r) * S_ + t + 1];

            const u64* tsw = hcur; hcur = hnxt; hnxt = (u64*)tsw;
        } else {
            if (g == 0) {
                #pragma unroll
                for (int r = 0; r < 4; ++r) {
                    int row = m0 + lq * 4 + r;
                    out[row * H_ + jg]               = hreg[r];
                    out[B_ * H_ + row * H_ + jg]     = hreg[r];
                    out[2 * B_ * H_ + row * H_ + jg] = creg[r];
                }
            }
        }
    }
}

extern "C" void kernel_launch(void* const* d_in, const int* in_sizes, int n_in,
                              void* d_out, int out_size, void* d_ws, size_t ws_size,
                              hipStream_t stream) {
    (void)in_sizes; (void)n_in; (void)out_size; (void)ws_size;
    const int*   tokens = (const int*)  d_in[0];
    const float* emb    = (const float*)d_in[1];
    const float* W      = (const float*)d_in[2];
    const float* U      = (const float*)d_in[3];
    const float* bias   = (const float*)d_in[4];

    char* ws = (char*)d_ws;
    ushort*        WT   = (ushort*)ws;                               // 4 MB
    unsigned char* UT   = (unsigned char*)(ws + (4u << 20));         // 4 MB fp8
    ushort*        xWT  = (ushort*)(ws + (8u << 20));                // 128 MB
    u64*           hA   = (u64*)(ws + (136u << 20));                 // 32 KB
    u64*           hB   = hA + 4096;                                 // 32 KB
    unsigned*      flags = (unsigned*)(hB + 4096);                   // 2 KB

    init_kernel<<<16, 256, 0, stream>>>(hA, flags);
    transpose_w_kernel<<<dim3(G4_ / 32, E_ / 32), 256, 0, stream>>>(W, WT);
    transpose_u_kernel<<<dim3(G4_ / 32, H_ / 32), 256, 0, stream>>>(U, (unsigned*)UT);
    gemm_xw_kernel<<<dim3(64, 256), 256, 0, stream>>>(tokens, emb, WT, bias, xWT);
    scan_kernel<<<256, 128, 0, stream>>>(UT, xWT, tokens, hA, hB, flags, (float*)d_out);
}

// Round 5
// 3279.800 us; speedup vs baseline: 2.0440x; 2.0440x over previous
//
#include <hip/hip_runtime.h>
#include <hip/hip_bf16.h>

// Problem constants
#define B_    32
#define S_    512
#define E_    512
#define H_    1024          // U_DIM
#define G4_   4096          // 4*U_DIM
#define NB_   64            // scan blocks (one wave0-poll lane per flag)
#define HPAD_ 1040          // Hs row stride bytes (1024 + 16 pad -> 2-way banks only)

typedef __attribute__((ext_vector_type(8))) short short8;
typedef __attribute__((ext_vector_type(4))) float f32x4;
typedef unsigned long long u64;

__device__ __forceinline__ float bf2f(ushort u) {
    union { unsigned u32; float f; } cv; cv.u32 = ((unsigned)u) << 16; return cv.f;
}
__device__ __forceinline__ ushort f2bf(float f) {
    union { float f; unsigned u; } cv; cv.f = f;
    unsigned u = cv.u;
    u += 0x7FFFu + ((u >> 16) & 1u);   // RNE
    return (ushort)(u >> 16);
}
__device__ __forceinline__ float tanh_fast(float x) {
    float e = __builtin_amdgcn_exp2f(x * 2.885390081777927f);
    return 1.0f - 2.0f * __builtin_amdgcn_rcpf(e + 1.0f);
}
__device__ __forceinline__ float sel4(int s, float a0, float a1, float a2, float a3) {
    return (s & 2) ? ((s & 1) ? a3 : a2) : ((s & 1) ? a1 : a0);
}

// ---------------- init: zero h0/flags, build per-step row masks ----------------
__global__ void init_kernel(const int* __restrict__ tokens, u64* hA, unsigned* flags,
                            unsigned* __restrict__ m32) {
    int i = blockIdx.x * 256 + threadIdx.x;   // grid 16x256 -> 0..4095
    if (i < 4096) hA[i] = 0ull;               // 32 KB fp8 h state
    if (i < NB_)  flags[i] = 0u;
    if (i < 512) {
        unsigned m = 0;
        for (int b = 0; b < 32; ++b)
            m |= (tokens[b * S_ + i] != 0 ? 1u : 0u) << b;
        m32[i] = m;
    }
}

// ---------------- W transpose: fp32 [E][G4] -> bf16 WT[n][k] ----------------
__global__ void transpose_w_kernel(const float* __restrict__ src, ushort* __restrict__ dst) {
    __shared__ float tile[32][33];
    int kx = blockIdx.y * 32;
    int nx = blockIdx.x * 32;
    int c  = threadIdx.x & 31;
    int r0 = threadIdx.x >> 5;
    for (int rr = r0; rr < 32; rr += 8)
        tile[rr][c] = src[(size_t)(kx + rr) * G4_ + nx + c];
    __syncthreads();
    for (int rr = r0; rr < 32; rr += 8)
        dst[(size_t)(nx + rr) * E_ + kx + c] = f2bf(tile[c][rr]);
}

// ---------------- U transpose: fp32 [H][G4] -> fp8(e4m3, x64) UT[n'][k], n'=j*4+g ----------------
__global__ void transpose_u_kernel(const float* __restrict__ src, unsigned* __restrict__ dst) {
    __shared__ float tile[32][33];
    int kx = blockIdx.y * 32;
    int nx = blockIdx.x * 32;
    int c  = threadIdx.x & 31;
    int r0 = threadIdx.x >> 5;
    for (int rr = r0; rr < 32; rr += 8)
        tile[rr][c] = src[(size_t)(kx + rr) * G4_ + nx + c];
    __syncthreads();
    int r  = threadIdx.x >> 3;    // n-index in tile 0..31
    int c3 = threadIdx.x & 7;     // k-quad
    int n  = nx + r;
    int np = (n & 1023) * 4 + (n >> 10);
    float v0 = tile[c3 * 4 + 0][r] * 64.0f;
    float v1 = tile[c3 * 4 + 1][r] * 64.0f;
    float v2 = tile[c3 * 4 + 2][r] * 64.0f;
    float v3 = tile[c3 * 4 + 3][r] * 64.0f;
    int pk = __builtin_amdgcn_cvt_pk_fp8_f32(v0, v1, 0, false);
    pk     = __builtin_amdgcn_cvt_pk_fp8_f32(v2, v3, pk, true);
    dst[((size_t)np * H_ + kx + c3 * 4) >> 2] = (unsigned)pk;
}

// ---------------- xW GEMM: emb[tok] @ W + b  -> xWT[t][n'][b] bf16 (coalesced via LDS) ----------------
__global__ __launch_bounds__(256, 1) void gemm_xw_kernel(
    const int* __restrict__ tokens, const float* __restrict__ emb,
    const ushort* __restrict__ WT,  const float* __restrict__ bias,
    ushort* __restrict__ xWT) {
    __shared__ u64 Cs[1024];
    const int tid  = threadIdx.x;
    const int lane = tid & 63;
    const int w    = tid >> 6;
    const int jb   = blockIdx.x;      // 0..63  (j-block of 16)
    const int mb   = blockIdx.y;      // 0..255 (t-pair)
    const int lr = lane & 15, lq = lane >> 4;

    const int t    = mb * 2 + (w >> 1);
    const int brow = (w & 1) * 16 + lr;
    const int tok  = tokens[brow * S_ + t];
    const float* arow = emb + (size_t)tok * E_;

    f32x4 acc[4] = {{0,0,0,0},{0,0,0,0},{0,0,0,0},{0,0,0,0}};
    #pragma unroll 4
    for (int ks = 0; ks < E_ / 32; ++ks) {
        const float* ap = arow + ks * 32 + lq * 8;
        float4 a0 = *reinterpret_cast<const float4*>(ap);
        float4 a1 = *reinterpret_cast<const float4*>(ap + 4);
        short8 af;
        af[0] = (short)f2bf(a0.x); af[1] = (short)f2bf(a0.y);
        af[2] = (short)f2bf(a0.z); af[3] = (short)f2bf(a0.w);
        af[4] = (short)f2bf(a1.x); af[5] = (short)f2bf(a1.y);
        af[6] = (short)f2bf(a1.z); af[7] = (short)f2bf(a1.w);
        #pragma unroll
        for (int s = 0; s < 4; ++s) {
            const ushort* brow_p = WT + (size_t)(s * 1024 + jb * 16 + lr) * E_;
            short8 bf = *reinterpret_cast<const short8*>(brow_p + ks * 32 + lq * 8);
            acc[s] = __builtin_amdgcn_mfma_f32_16x16x32_bf16(af, bf, acc[s], 0, 0, 0);
        }
    }
    #pragma unroll
    for (int s = 0; s < 4; ++s) {
        float bv = bias[s * 1024 + jb * 16 + lr];
        u64 pk = 0;
        #pragma unroll
        for (int r = 0; r < 4; ++r)
            pk |= (u64)f2bf(acc[s][r] + bv) << (16 * r);
        int npl = lr * 4 + s;
        int b4  = (w & 1) * 4 + lq;
        Cs[((w >> 1) * 64 + npl) * 8 + b4] = pk;
    }
    __syncthreads();
    #pragma unroll
    for (int i = 0; i < 4; ++i) {
        int e   = tid + i * 256;
        int tp  = e >> 9;
        int rem = e & 511;
        size_t base = ((size_t)(mb * 2 + tp) * G4_ + jb * 64) * B_;
        *reinterpret_cast<u64*>(xWT + base + rem * 4) = Cs[e];
    }
}

// ---------------- persistent LSTM scan ----------------
// 64 blocks x 256 thr. Block = 32 rows x 64 n'-cols. U fragments pinned in VGPRs
// (asm "+v" blocks rematerialization). h (fp8) via LLC with proven tmp[]->LDS
// staging. Distributed barrier: 64 per-block flags, wave0 polls all directly.
__global__ __launch_bounds__(256, 1) void scan_kernel(
    const unsigned char* __restrict__ UT,  // fp8 [4096][1024]
    const ushort* __restrict__ xWT,        // bf16 [512][4096][32]
    const unsigned* __restrict__ m32,      // [512] row masks
    u64* hA, u64* hB,                      // fp8 h [32][1024] ping-pong
    unsigned* flags,                       // [64] per-block step counters
    float* __restrict__ out) {             // [3][32][1024] fp32
    __shared__ unsigned char Hs[32 * HPAD_];   // 33.3 KB fp8 h stage

    const int tid  = threadIdx.x;
    const int blk  = blockIdx.x;
    const int lane = tid & 63;
    const int w    = tid >> 6;            // 0..3
    const int lr = lane & 15, lq = lane >> 4;
    const int m0 = (w & 1) * 16;          // row group
    const int n0 = blk * 64 + (w >> 1) * 32;
    const int c0 = n0 + lr;               // tile0 global n'
    const int c1 = n0 + 16 + lr;          // tile1 global n'
    const int g  = lr & 3;                // gate id

    // step-invariant B fragments -> 128 pinned VGPRs
    u64 ub0[32], ub1[32];
    #pragma unroll
    for (int ks = 0; ks < 32; ++ks) {
        ub0[ks] = *reinterpret_cast<const u64*>(UT + (size_t)c0 * H_ + ks * 32 + lq * 8);
        ub1[ks] = *reinterpret_cast<const u64*>(UT + (size_t)c1 * H_ + ks * 32 + lq * 8);
    }
    #pragma unroll
    for (int ks = 0; ks < 32; ++ks) {
        asm volatile("" : "+v"(ub0[ks]));
        asm volatile("" : "+v"(ub1[ks]));
    }

    float creg0[4] = {0,0,0,0}, hreg0[4] = {0,0,0,0};
    float creg1[4] = {0,0,0,0}, hreg1[4] = {0,0,0,0};

    const u64* hcur = hA;
    u64*       hnxt = hB;

    // t=0 inputs
    u64 xwv0 = *reinterpret_cast<const u64*>(xWT + ((size_t)0 * G4_ + c0) * B_ + m0 + lq * 4);
    u64 xwv1 = *reinterpret_cast<const u64*>(xWT + ((size_t)0 * G4_ + c1) * B_ + m0 + lq * 4);
    unsigned mask = m32[0];

    for (int t = 0; t < S_; ++t) {
        // ---- stage h (LLC) -> LDS via explicit tmp[] (pipelined) ----
        u64 tmp[16];
        #pragma unroll
        for (int i = 0; i < 16; ++i)
            tmp[i] = __hip_atomic_load(hcur + tid + i * 256,
                                       __ATOMIC_RELAXED, __HIP_MEMORY_SCOPE_AGENT);
        #pragma unroll
        for (int i = 0; i < 16; ++i) {
            int e = tid + i * 256, row = e >> 7, kc = e & 127;
            *reinterpret_cast<u64*>(&Hs[row * HPAD_ + kc * 8]) = tmp[i];
        }
        __syncthreads();

        // ---- z-tiles = h @ U (fp8 MFMA, K=1024, shared A-frag) ----
        f32x4 acc0 = {0,0,0,0}, acc1 = {0,0,0,0};
        #pragma unroll
        for (int ks = 0; ks < 32; ++ks) {
            u64 af = *reinterpret_cast<const u64*>(&Hs[(m0 + lr) * HPAD_ + ks * 32 + lq * 8]);
            acc0 = __builtin_amdgcn_mfma_f32_16x16x32_fp8_fp8((long)af, (long)ub0[ks], acc0, 0, 0, 0);
            acc1 = __builtin_amdgcn_mfma_f32_16x16x32_fp8_fp8((long)af, (long)ub1[ks], acc1, 0, 0, 0);
        }

        // ---- gates ----
        #pragma unroll
        for (int r = 0; r < 4; ++r) {
            bool mb = (mask >> (m0 + lq * 4 + r)) & 1;
            {
                float z  = acc0[r] * (1.0f / 16384.0f) + bf2f((ushort)(xwv0 >> (16 * r)));
                float tg = tanh_fast(z);
                float x1 = __shfl_xor(tg, 1, 64);
                float x2 = __shfl_xor(tg, 2, 64);
                float x3 = __shfl_xor(tg, 3, 64);
                float tI = sel4(g,     tg, x1, x2, x3);
                float tF = sel4(g ^ 1, tg, x1, x2, x3);
                float tG = sel4(g ^ 2, tg, x1, x2, x3);
                float tO = sel4(g ^ 3, tg, x1, x2, x3);
                float cn = tF * creg0[r] + tI * tG;
                float hn = tO * tanh_fast(cn);
                if (mb) { creg0[r] = cn; hreg0[r] = hn; }
            }
            {
                float z  = acc1[r] * (1.0f / 16384.0f) + bf2f((ushort)(xwv1 >> (16 * r)));
                float tg = tanh_fast(z);
                float x1 = __shfl_xor(tg, 1, 64);
                float x2 = __shfl_xor(tg, 2, 64);
                float x3 = __shfl_xor(tg, 3, 64);
                float tI = sel4(g,     tg, x1, x2, x3);
                float tF = sel4(g ^ 1, tg, x1, x2, x3);
                float tG = sel4(g ^ 2, tg, x1, x2, x3);
                float tO = sel4(g ^ 3, tg, x1, x2, x3);
                float cn = tF * creg1[r] + tI * tG;
                float hn = tO * tanh_fast(cn);
                if (mb) { creg1[r] = cn; hreg1[r] = hn; }
            }
        }

        if (t < S_ - 1) {
            // ---- pack 8 j-cols (fp8 x256) per row -> one u64 store on lr==0 lanes ----
            #pragma unroll
            for (int r = 0; r < 4; ++r) {
                float a0 = hreg0[r] * 256.0f;
                float b0 = __shfl_xor(a0, 4, 64);
                float cc0 = __shfl_xor(a0, 8, 64);
                float d0 = __shfl_xor(a0, 12, 64);
                int pk0 = __builtin_amdgcn_cvt_pk_fp8_f32(a0, b0, 0, false);
                pk0     = __builtin_amdgcn_cvt_pk_fp8_f32(cc0, d0, pk0, true);
                float a1 = hreg1[r] * 256.0f;
                float b1 = __shfl_xor(a1, 4, 64);
                float cc1 = __shfl_xor(a1, 8, 64);
                float d1 = __shfl_xor(a1, 12, 64);
                int pk1 = __builtin_amdgcn_cvt_pk_fp8_f32(a1, b1, 0, false);
                pk1     = __builtin_amdgcn_cvt_pk_fp8_f32(cc1, d1, pk1, true);
                if (lr == 0) {
                    int row = m0 + lq * 4 + r;
                    u64 pv = (u64)(unsigned)pk0 | ((u64)(unsigned)pk1 << 32);
                    __hip_atomic_store(hnxt + row * 128 + blk * 2 + (w >> 1), pv,
                                       __ATOMIC_RELAXED, __HIP_MEMORY_SCOPE_AGENT);
                }
            }
            __syncthreads();              // drains all waves' h stores (vmcnt 0)
            if (tid == 0)
                __hip_atomic_store(&flags[blk], (unsigned)(t + 1),
                                   __ATOMIC_RELAXED, __HIP_MEMORY_SCOPE_AGENT);
            // prefetch next-step inputs during the poll
            xwv0 = *reinterpret_cast<const u64*>(xWT + ((size_t)(t + 1) * G4_ + c0) * B_ + m0 + lq * 4);
            xwv1 = *reinterpret_cast<const u64*>(xWT + ((size_t)(t + 1) * G4_ + c1) * B_ + m0 + lq * 4);
            mask = m32[t + 1];
            if (w == 0) {
                unsigned tv = (unsigned)(t + 1);
                for (;;) {
                    unsigned f = __hip_atomic_load(&flags[lane],
                                                   __ATOMIC_RELAXED, __HIP_MEMORY_SCOPE_AGENT);
                    if (__all(f >= tv)) break;
                    __builtin_amdgcn_s_sleep(1);
                }
            }
            __syncthreads();              // all blocks arrived -> safe to read hnxt
            const u64* tsw = hcur; hcur = hnxt; hnxt = (u64*)tsw;
        } else {
            // ---- final: write (h, h, c) fp32 ----
            if (g == 0) {
                int j0 = c0 >> 2, j1 = c1 >> 2;
                #pragma unroll
                for (int r = 0; r < 4; ++r) {
                    int row = m0 + lq * 4 + r;
                    out[row * H_ + j0]               = hreg0[r];
                    out[B_ * H_ + row * H_ + j0]     = hreg0[r];
                    out[2 * B_ * H_ + row * H_ + j0] = creg0[r];
                    out[row * H_ + j1]               = hreg1[r];
                    out[B_ * H_ + row * H_ + j1]     = hreg1[r];
                    out[2 * B_ * H_ + row * H_ + j1] = creg1[r];
                }
            }
        }
    }
}

extern "C" void kernel_launch(void* const* d_in, const int* in_sizes, int n_in,
                              void* d_out, int out_size, void* d_ws, size_t ws_size,
                              hipStream_t stream) {
    (void)in_sizes; (void)n_in; (void)out_size; (void)ws_size;
    const int*   tokens = (const int*)  d_in[0];
    const float* emb    = (const float*)d_in[1];
    const float* W      = (const float*)d_in[2];
    const float* U      = (const float*)d_in[3];
    const float* bias   = (const float*)d_in[4];

    char* ws = (char*)d_ws;
    ushort*        WT    = (ushort*)ws;                               // 4 MB
    unsigned char* UT    = (unsigned char*)(ws + (4u << 20));         // 4 MB fp8
    ushort*        xWT   = (ushort*)(ws + (8u << 20));                // 128 MB
    u64*           hA    = (u64*)(ws + (136u << 20));                 // 32 KB
    u64*           hB    = hA + 4096;                                 // 32 KB
    unsigned*      flags = (unsigned*)(hB + 4096);                    // 256 B
    unsigned*      m32   = flags + 64;                                // 2 KB

    init_kernel<<<16, 256, 0, stream>>>(tokens, hA, flags, m32);
    transpose_w_kernel<<<dim3(G4_ / 32, E_ / 32), 256, 0, stream>>>(W, WT);
    transpose_u_kernel<<<dim3(G4_ / 32, H_ / 32), 256, 0, stream>>>(U, (unsigned*)UT);
    gemm_xw_kernel<<<dim3(64, 256), 256, 0, stream>>>(tokens, emb, WT, bias, xWT);
    scan_kernel<<<NB_, 256, 0, stream>>>(UT, xWT, m32, hA, hB, flags, (float*)d_out);
}